// Round 3
// baseline (12.721 us; speedup 1.0000x reference)
//
#include <hip/hip_runtime.h>

// MPSELoss one-dispatch, multi-block:
// loss = sum_b [ N*sum_i d_bi^2 - (sum_i d_bi)^2 ] / (B * N*(N-1)/2),  d = outputs - targets
// 32 blocks (one per row) x 256 threads. Each block reduces its row, release-stores a
// double partial into its own d_ws slot, then bumps an arrival counter. The block whose
// fetch_add return is ==31 (mod 32) is last; it acquire-loads all 32 slots in fixed index
// order and writes the scalar. Counter needs no init: any start value works mod 32, and
// integer atomics keep everything bit-deterministic.

#define BB 32
#define NN 2048

__global__ void __launch_bounds__(256) mpse_onepass(const float* __restrict__ outs,
                                                    const float* __restrict__ tgts,
                                                    double* __restrict__ partials,
                                                    unsigned int* __restrict__ counter,
                                                    float* __restrict__ out) {
    const int row = blockIdx.x;
    const int t = threadIdx.x;

    const float4* o4 = reinterpret_cast<const float4*>(outs + (size_t)row * NN);
    const float4* g4 = reinterpret_cast<const float4*>(tgts + (size_t)row * NN);

    float s1 = 0.f, s2 = 0.f;
    // 512 float4 per row; 256 threads -> 2 float4 each, coalesced.
#pragma unroll
    for (int k = 0; k < 2; ++k) {
        float4 a = o4[t + k * 256];
        float4 b = g4[t + k * 256];
        float d0 = a.x - b.x;
        float d1 = a.y - b.y;
        float d2 = a.z - b.z;
        float d3 = a.w - b.w;
        s1 += (d0 + d1) + (d2 + d3);
        s2 += (d0 * d0 + d1 * d1) + (d2 * d2 + d3 * d3);
    }

    // wave64 butterfly
#pragma unroll
    for (int off = 32; off >= 1; off >>= 1) {
        s1 += __shfl_xor(s1, off);
        s2 += __shfl_xor(s2, off);
    }

    __shared__ float sh1[4];
    __shared__ float sh2[4];
    const int wave = t >> 6;
    if ((t & 63) == 0) {
        sh1[wave] = s1;
        sh2[wave] = s2;
    }
    __syncthreads();

    if (t == 0) {
        float S1 = (sh1[0] + sh1[1]) + (sh1[2] + sh1[3]);
        float S2 = (sh2[0] + sh2[1]) + (sh2[2] + sh2[3]);
        double val = (double)NN * (double)S2 - (double)S1 * (double)S1;

        __hip_atomic_store(&partials[row], val, __ATOMIC_RELEASE, __HIP_MEMORY_SCOPE_AGENT);
        unsigned int prev = __hip_atomic_fetch_add(counter, 1u, __ATOMIC_ACQ_REL,
                                                   __HIP_MEMORY_SCOPE_AGENT);
        if ((prev & (BB - 1)) == (BB - 1)) {
            // last arrival: all 32 release-stores of this call are visible
            double acc = 0.0;
#pragma unroll
            for (int r = 0; r < BB; ++r) {
                acc += __hip_atomic_load(&partials[r], __ATOMIC_ACQUIRE,
                                         __HIP_MEMORY_SCOPE_AGENT);
            }
            const double count = (double)BB * ((double)NN * (double)(NN - 1) * 0.5);
            out[0] = (float)(acc / count);
        }
    }
}

extern "C" void kernel_launch(void* const* d_in, const int* in_sizes, int n_in,
                              void* d_out, int out_size, void* d_ws, size_t ws_size,
                              hipStream_t stream) {
    const float* outs = (const float*)d_in[0];
    const float* tgts = (const float*)d_in[1];
    float* out = (float*)d_out;                      // 1 float
    double* partials = (double*)d_ws;                // 32 doubles
    unsigned int* counter = (unsigned int*)((char*)d_ws + BB * sizeof(double));

    mpse_onepass<<<dim3(BB), dim3(256), 0, stream>>>(outs, tgts, partials, counter, out);
}